// Round 4
// baseline (904.168 us; speedup 1.0000x reference)
//
#include <hip/hip_runtime.h>
#include <math.h>
#include <float.h>

// EMAVectorQuantizer eval path.
//   z: [8, 64, 64, 64] fp32  (B, C=d=64, H, W);  weight: [4096, 64] fp32
//   N = 32768 rows, K = 4096 codes.
//
// d_out (flat fp32): z_q[2097152] | loss | perplexity | encodings[32768*4096] | indices[32768]
#define ZQ_OFF   0
#define LOSS_OFF 2097152
#define PERP_OFF 2097153
#define ENC_OFF  2097154
#define IDX_OFF  136314882ULL
#define BETA     0.25f

// ws layout: [0..4) loss fp32 acc | [4..8) ticket int | [16..16+16384) hist int[4096]
//            [16400 .. +16384) wnorm fp32[4096]

__global__ void vq_wnorm(const float* __restrict__ w, float* __restrict__ wnorm) {
    int c = blockIdx.x * 256 + threadIdx.x;
    const float4* w4 = (const float4*)(w + ((size_t)c << 6));
    float s = 0.f;
    #pragma unroll
    for (int k = 0; k < 16; ++k) { float4 v = w4[k]; s += v.x*v.x + v.y*v.y + v.z*v.z + v.w*v.w; }
    wnorm[c] = s;
}

// Block: 256 threads = 8 row-groups x 32 col-groups. Per-thread tile: 8 rows x 8 codes.
// Chunk = 256 codes, d staged in 2 x 32 slices (32 phases). Register-double-buffered w.
__global__ __launch_bounds__(256, 2) void vq_main(
    const float* __restrict__ z, const float* __restrict__ w,
    const float* __restrict__ wnorm, float* __restrict__ out,
    float* __restrict__ loss_ws, int* __restrict__ ticket, int* __restrict__ hist)
{
    __shared__ float zD[64][64];     // [d][w-row]
    __shared__ float wl[256 * 36];   // [c_local][36]: 32-d slice, stride 36 (start-bank spread 4)
    __shared__ int   s_widx[64];
    __shared__ int   s_flag;

    const int tx   = threadIdx.x;
    const int tcol = tx & 31;            // codes tcol + 32k, k=0..7, within chunk
    const int trow = tx >> 5;            // rows trow*8 .. trow*8+7 within block
    const int base = blockIdx.x * 64;    // global rows [base, base+64)
    const int bb   = base >> 12;         // b
    const int hh   = (base & 4095) >> 6; // h   (w coordinate = row-in-block)

    // staging geometry (fixed per thread): slice element = pw[j] -> wl[c*36 + q*4]
    const int sc = tx >> 3;              // this thread's base code (with +32j)... see loop: c = (j*256+tx)>>3
    const int sq = tx & 7;
    (void)sc; (void)sq;

    // ---- stage zD[d][wcol] = z[bb][d][hh][wcol] ----
    #pragma unroll
    for (int j = 0; j < 4; ++j) {
        int f4 = j * 256 + tx;
        int d  = f4 >> 4, w4i = f4 & 15;
        float4 v = *(const float4*)(z + (((size_t)bb * 64 + d) * 64 + hh) * 64 + w4i * 4);
        *(float4*)&zD[d][w4i * 4] = v;
    }

    float best[8]; int bidx[8];
    #pragma unroll
    for (int i = 0; i < 8; ++i) { best[i] = FLT_MAX; bidx[i] = 0; }

    float* enc = out + ENC_OFF;          // 8-byte aligned -> float2 stores

    // prologue: prefetch phase-0 w slice into registers
    float4 pw[8];
    #pragma unroll
    for (int j = 0; j < 8; ++j) {
        int f4 = j * 256 + tx;
        int c  = f4 >> 3, q = f4 & 7;
        pw[j] = ((const float4*)w)[(size_t)c * 16 + q];   // cbase=0, s=0
    }

    float acc[8][8];
    float wn[8];

    for (int p = 0; p < 32; ++p) {
        const int ch = p >> 1, s = p & 1;
        const int cbase = ch << 8;

        __syncthreads();                 // previous-phase wl readers done
        #pragma unroll
        for (int j = 0; j < 8; ++j) {
            int f4 = j * 256 + tx;
            int c  = f4 >> 3, q = f4 & 7;
            *(float4*)&wl[c * 36 + q * 4] = pw[j];
        }
        __syncthreads();                 // wl ready (lgkm drain only; no pending vmem)

        // prefetch NEXT phase's w slice (in flight during the whole compute phase)
        {
            const int pn = (p < 31) ? p + 1 : 31;
            const int cbn = (pn >> 1) << 8, sn = pn & 1;
            #pragma unroll
            for (int j = 0; j < 8; ++j) {
                int f4 = j * 256 + tx;
                int c  = f4 >> 3, q = f4 & 7;
                pw[j] = ((const float4*)w)[(size_t)(cbn + c) * 16 + sn * 8 + q];
            }
        }
        // zero-fill encodings: non-temporal (don't thrash L2/L3), retires during compute
        #pragma unroll
        for (int j = 0; j < 16; ++j) {
            int f2 = (p * 16 + j) * 256 + tx;        // 0..131071 float2 slots
            int r  = f2 >> 11, c2 = f2 & 2047;
            double* dp = (double*)((float2*)(enc + ((size_t)(base + r) << 12)) + c2);
            __builtin_nontemporal_store(0.0, dp);
        }

        if (s == 0) {
            #pragma unroll
            for (int k = 0; k < 8; ++k) wn[k] = wnorm[cbase + tcol + 32 * k];
            #pragma unroll
            for (int i = 0; i < 8; ++i)
                #pragma unroll
                for (int k = 0; k < 8; ++k) acc[i][k] = 0.f;
        }

        // compute this 32-d slice: 8 groups of 4 d's
        #pragma unroll
        for (int dg = 0; dg < 8; ++dg) {
            const int d0 = s * 32 + dg * 4;
            float4 zv0[4], zv1[4];
            #pragma unroll
            for (int e = 0; e < 4; ++e) {
                zv0[e] = *(const float4*)&zD[d0 + e][trow * 8];
                zv1[e] = *(const float4*)&zD[d0 + e][trow * 8 + 4];
            }
            float4 wv[8];
            #pragma unroll
            for (int k = 0; k < 8; ++k)
                wv[k] = *(const float4*)&wl[(tcol + 32 * k) * 36 + dg * 4];
            #pragma unroll
            for (int k = 0; k < 8; ++k) {
                #pragma unroll
                for (int e = 0; e < 4; ++e) {
                    const float wf = (e == 0) ? wv[k].x : (e == 1) ? wv[k].y
                                    : (e == 2) ? wv[k].z : wv[k].w;
                    acc[0][k] = fmaf(zv0[e].x, wf, acc[0][k]);
                    acc[1][k] = fmaf(zv0[e].y, wf, acc[1][k]);
                    acc[2][k] = fmaf(zv0[e].z, wf, acc[2][k]);
                    acc[3][k] = fmaf(zv0[e].w, wf, acc[3][k]);
                    acc[4][k] = fmaf(zv1[e].x, wf, acc[4][k]);
                    acc[5][k] = fmaf(zv1[e].y, wf, acc[5][k]);
                    acc[6][k] = fmaf(zv1[e].z, wf, acc[6][k]);
                    acc[7][k] = fmaf(zv1[e].w, wf, acc[7][k]);
                }
            }
        }

        if (s == 1) {
            // fold into running argmin (codes ascending per thread: k then chunk order)
            #pragma unroll
            for (int i = 0; i < 8; ++i) {
                #pragma unroll
                for (int k = 0; k < 8; ++k) {
                    float scv = fmaf(-2.f, acc[i][k], wn[k]);
                    if (scv < best[i]) { best[i] = scv; bidx[i] = cbase + tcol + 32 * k; }
                }
            }
        }
    }

    // ---- cross-thread argmin reduce (reuse wl as [64][32] float2) ----
    __syncthreads();                       // drains all zero-fill stores too
    float2* red = (float2*)wl;
    #pragma unroll
    for (int i = 0; i < 8; ++i)
        red[(trow * 8 + i) * 32 + tcol] = make_float2(best[i], __int_as_float(bidx[i]));
    __syncthreads();

    if (tx < 64) {
        float b = FLT_MAX; int bi = 0x7fffffff;
        for (int c = 0; c < 32; ++c) {
            float2 v = red[tx * 32 + c];
            int vi = __float_as_int(v.y);
            if (v.x < b || (v.x == b && vi < bi)) { b = v.x; bi = vi; }
        }
        s_widx[tx] = bi;
        out[IDX_OFF + (size_t)(base + tx)] = (float)bi;
        atomicAdd(&hist[bi], 1);
        enc[((size_t)(base + tx) << 12) + bi] = 1.0f;   // zero-fill drained at barrier above
    }
    __syncthreads();

    // ---- z_q (STE rounding) + commitment loss partial ----
    {
        const int row = tx & 63;
        const int dg  = tx >> 6;           // 4 waves x 16 d each
        const int wi  = s_widx[row];
        const float* qrow = w + ((size_t)wi << 6);
        float lsum = 0.f;
        #pragma unroll
        for (int dd = 0; dd < 16; ++dd) {
            int d = dg * 16 + dd;
            float q  = qrow[d];
            float zv = zD[d][row];
            float diff = q - zv;
            lsum += diff * diff;
            out[ZQ_OFF + (((size_t)bb * 64 + d) * 64 + hh) * 64 + row] = zv + (q - zv);
        }
        #pragma unroll
        for (int off = 32; off > 0; off >>= 1) lsum += __shfl_down(lsum, off, 64);
        if ((tx & 63) == 0) atomicAdd(loss_ws, lsum);
    }

    // ---- fused finalize: last block computes loss scalar + perplexity ----
    __syncthreads();
    if (tx == 0) {
        __threadfence();
        int old = atomicAdd(ticket, 1);
        s_flag = (old == 511) ? 1 : 0;
    }
    __syncthreads();
    if (s_flag) {
        __threadfence();
        float s = 0.f;
        #pragma unroll
        for (int j = 0; j < 16; ++j) {
            int c = tx + j * 256;
            int cnt = atomicAdd(&hist[c], 0);          // device-coherent read
            float p = (float)cnt * (1.f / 32768.f);
            s += p * logf(p + 1e-10f);
        }
        float* fr = wl;
        fr[tx] = s;
        __syncthreads();
        for (int off = 128; off > 0; off >>= 1) {
            if (tx < off) fr[tx] += fr[tx + off];
            __syncthreads();
        }
        if (tx == 0) {
            out[LOSS_OFF] = BETA * atomicAdd(loss_ws, 0.f) / 2097152.f;
            out[PERP_OFF] = expf(-fr[0]);
        }
    }
}

extern "C" void kernel_launch(void* const* d_in, const int* in_sizes, int n_in,
                              void* d_out, int out_size, void* d_ws, size_t ws_size,
                              hipStream_t stream)
{
    const float* z = (const float*)d_in[0];
    const float* w = (const float*)d_in[1];
    float* out     = (float*)d_out;
    float* loss_ws = (float*)d_ws;
    int*   ticket  = (int*)((char*)d_ws + 4);
    int*   hist    = (int*)((char*)d_ws + 16);
    float* wnorm   = (float*)((char*)d_ws + 16400);

    hipMemsetAsync(d_ws, 0, 16 + 4096 * sizeof(int), stream);
    vq_wnorm<<<16, 256, 0, stream>>>(w, wnorm);
    vq_main<<<512, 256, 0, stream>>>(z, w, wnorm, out, loss_ws, ticket, hist);
}

// Round 5
// 851.920 us; speedup vs baseline: 1.0613x; 1.0613x over previous
//
#include <hip/hip_runtime.h>
#include <math.h>
#include <float.h>

// EMAVectorQuantizer eval path.
//   z: [8, 64, 64, 64] fp32  (B, C=d=64, H, W);  weight: [4096, 64] fp32
//   N = 32768 rows, K = 4096 codes.
//
// d_out (flat fp32): z_q[2097152] | loss | perplexity | encodings[32768*4096] | indices[32768]
#define ZQ_OFF   0
#define LOSS_OFF 2097152
#define PERP_OFF 2097153
#define ENC_OFF  2097154
#define IDX_OFF  136314882ULL
#define BETA     0.25f

#define WSTRIDE  34   // 2-way start-bank aliasing (free per m136); 4-way at 36 costs 1.58x

// ws layout: [0..4) loss fp32 acc | [4..8) ticket int | [16..16+16384) hist int[4096]
//            [16400 .. +16384) wnorm fp32[4096]

__global__ void vq_wnorm(const float* __restrict__ w, float* __restrict__ wnorm) {
    int c = blockIdx.x * 256 + threadIdx.x;
    const float4* w4 = (const float4*)(w + ((size_t)c << 6));
    float s = 0.f;
    #pragma unroll
    for (int k = 0; k < 16; ++k) { float4 v = w4[k]; s += v.x*v.x + v.y*v.y + v.z*v.z + v.w*v.w; }
    wnorm[c] = s;
}

// acc[i][k] += z_row_i[d] * w_code_k[d], d ascending (bit-identical chain to prior rounds)
#define FMA8(ZA, ZB, WF, K) \
    acc[0][K] = fmaf((ZA).x, (WF), acc[0][K]); \
    acc[1][K] = fmaf((ZA).y, (WF), acc[1][K]); \
    acc[2][K] = fmaf((ZA).z, (WF), acc[2][K]); \
    acc[3][K] = fmaf((ZA).w, (WF), acc[3][K]); \
    acc[4][K] = fmaf((ZB).x, (WF), acc[4][K]); \
    acc[5][K] = fmaf((ZB).y, (WF), acc[5][K]); \
    acc[6][K] = fmaf((ZB).z, (WF), acc[6][K]); \
    acc[7][K] = fmaf((ZB).w, (WF), acc[7][K]);

// Block: 256 threads = 8 row-groups x 32 col-groups. Per-thread tile: 8 rows x 8 codes.
// Chunk = 256 codes, d staged in 2 x 32 slices (32 phases). Register-double-buffered w.
__global__ __launch_bounds__(256, 2) void vq_main(
    const float* __restrict__ z, const float* __restrict__ w,
    const float* __restrict__ wnorm, float* __restrict__ out,
    float* __restrict__ loss_ws, int* __restrict__ ticket, int* __restrict__ hist)
{
    __shared__ float zD[64][64];         // [d][w-row]
    __shared__ float wl[256 * WSTRIDE];  // [c_local][d-slice], 34.8 KB
    __shared__ int   s_widx[64];
    __shared__ int   s_flag;

    const int tx   = threadIdx.x;
    const int tcol = tx & 31;            // codes tcol + 32k, k=0..7, within chunk
    const int trow = tx >> 5;            // rows trow*8 .. trow*8+7 within block
    const int base = blockIdx.x * 64;    // global rows [base, base+64)
    const int bb   = base >> 12;         // b
    const int hh   = (base & 4095) >> 6; // h   (w coordinate = row-in-block)

    // ---- stage zD[d][wcol] = z[bb][d][hh][wcol] ----
    #pragma unroll
    for (int j = 0; j < 4; ++j) {
        int f4 = j * 256 + tx;
        int d  = f4 >> 4, w4i = f4 & 15;
        float4 v = *(const float4*)(z + (((size_t)bb * 64 + d) * 64 + hh) * 64 + w4i * 4);
        *(float4*)&zD[d][w4i * 4] = v;
    }

    float best[8]; int bidx[8];
    #pragma unroll
    for (int i = 0; i < 8; ++i) { best[i] = FLT_MAX; bidx[i] = 0; }

    float* enc = out + ENC_OFF;          // 8-byte aligned -> float2 stores

    // prologue: prefetch phase-0 w slice into registers
    const int stc = tx >> 3;             // staging code row base (with +32j per j)
    const int stq = tx & 7;              // staging quad within 32-float slice
    float4 pw[8];
    #pragma unroll
    for (int j = 0; j < 8; ++j)
        pw[j] = ((const float4*)w)[(size_t)(j * 32 + stc) * 16 + stq];   // cbase=0, s=0

    float acc[8][8];
    float wn[8];

    for (int p = 0; p < 32; ++p) {
        const int ch = p >> 1, s = p & 1;
        const int cbase = ch << 8;

        __syncthreads();                 // previous-phase wl readers done
        #pragma unroll
        for (int j = 0; j < 8; ++j)
            *(float4*)&wl[(j * 32 + stc) * WSTRIDE + stq * 4] = pw[j];
        __syncthreads();                 // wl ready

        // prefetch NEXT phase's w slice (lands during this phase's compute)
        {
            const int pn = (p < 31) ? p + 1 : 31;
            const int cbn = (pn >> 1) << 8, sn = pn & 1;
            #pragma unroll
            for (int j = 0; j < 8; ++j)
                pw[j] = ((const float4*)w)[(size_t)(cbn + j * 32 + stc) * 16 + sn * 8 + stq];
        }
        // zero-fill encodings: plain stores, retire during compute (drained at next barrier)
        #pragma unroll
        for (int j = 0; j < 16; ++j) {
            int f2 = (p * 16 + j) * 256 + tx;        // 0..131071 float2 slots
            int r  = f2 >> 11, c2 = f2 & 2047;
            *((float2*)(enc + ((size_t)(base + r) << 12)) + c2) = make_float2(0.f, 0.f);
        }

        if (s == 0) {
            #pragma unroll
            for (int k = 0; k < 8; ++k) wn[k] = wnorm[cbase + tcol + 32 * k];
            #pragma unroll
            for (int i = 0; i < 8; ++i)
                #pragma unroll
                for (int k = 0; k < 8; ++k) acc[i][k] = 0.f;
        }

        // compute this 32-d slice: 8 groups of 4 d's, fully explicit components
        #pragma unroll
        for (int dg = 0; dg < 8; ++dg) {
            const int d0 = s * 32 + dg * 4;
            float4 za0 = *(const float4*)&zD[d0    ][trow * 8];
            float4 zb0 = *(const float4*)&zD[d0    ][trow * 8 + 4];
            float4 za1 = *(const float4*)&zD[d0 + 1][trow * 8];
            float4 zb1 = *(const float4*)&zD[d0 + 1][trow * 8 + 4];
            float4 za2 = *(const float4*)&zD[d0 + 2][trow * 8];
            float4 zb2 = *(const float4*)&zD[d0 + 2][trow * 8 + 4];
            float4 za3 = *(const float4*)&zD[d0 + 3][trow * 8];
            float4 zb3 = *(const float4*)&zD[d0 + 3][trow * 8 + 4];
            #pragma unroll
            for (int k = 0; k < 8; ++k) {
                float4 wv = *(const float4*)&wl[(tcol + 32 * k) * WSTRIDE + dg * 4];
                FMA8(za0, zb0, wv.x, k);
                FMA8(za1, zb1, wv.y, k);
                FMA8(za2, zb2, wv.z, k);
                FMA8(za3, zb3, wv.w, k);
            }
        }

        if (s == 1) {
            // fold into running argmin (codes ascending per thread: k then chunk order)
            #pragma unroll
            for (int i = 0; i < 8; ++i) {
                #pragma unroll
                for (int k = 0; k < 8; ++k) {
                    float scv = fmaf(-2.f, acc[i][k], wn[k]);
                    if (scv < best[i]) { best[i] = scv; bidx[i] = cbase + tcol + 32 * k; }
                }
            }
        }
    }

    // ---- cross-thread argmin reduce (reuse wl as [64][32] float2) ----
    __syncthreads();                       // drains remaining zero-fill stores too
    float2* red = (float2*)wl;
    #pragma unroll
    for (int i = 0; i < 8; ++i)
        red[(trow * 8 + i) * 32 + tcol] = make_float2(best[i], __int_as_float(bidx[i]));
    __syncthreads();

    if (tx < 64) {
        float b = FLT_MAX; int bi = 0x7fffffff;
        for (int c = 0; c < 32; ++c) {
            float2 v = red[tx * 32 + c];
            int vi = __float_as_int(v.y);
            if (v.x < b || (v.x == b && vi < bi)) { b = v.x; bi = vi; }
        }
        s_widx[tx] = bi;
        out[IDX_OFF + (size_t)(base + tx)] = (float)bi;
        atomicAdd(&hist[bi], 1);
        enc[((size_t)(base + tx) << 12) + bi] = 1.0f;   // zero-fill drained at barrier above
    }
    __syncthreads();

    // ---- z_q (STE rounding) + commitment loss partial ----
    {
        const int row = tx & 63;
        const int dg  = tx >> 6;           // 4 waves x 16 d each
        const int wi  = s_widx[row];
        const float* qrow = w + ((size_t)wi << 6);
        float lsum = 0.f;
        #pragma unroll
        for (int dd = 0; dd < 16; ++dd) {
            int d = dg * 16 + dd;
            float q  = qrow[d];
            float zv = zD[d][row];
            float diff = q - zv;
            lsum += diff * diff;
            out[ZQ_OFF + (((size_t)bb * 64 + d) * 64 + hh) * 64 + row] = zv + (q - zv);
        }
        #pragma unroll
        for (int off = 32; off > 0; off >>= 1) lsum += __shfl_down(lsum, off, 64);
        if ((tx & 63) == 0) atomicAdd(loss_ws, lsum);
    }

    // ---- fused finalize: last block computes loss scalar + perplexity ----
    __syncthreads();
    if (tx == 0) {
        __threadfence();
        int old = atomicAdd(ticket, 1);
        s_flag = (old == 511) ? 1 : 0;
    }
    __syncthreads();
    if (s_flag) {
        __threadfence();
        float s = 0.f;
        #pragma unroll
        for (int j = 0; j < 16; ++j) {
            int c = tx + j * 256;
            int cnt = atomicAdd(&hist[c], 0);          // device-coherent read
            float p = (float)cnt * (1.f / 32768.f);
            s += p * logf(p + 1e-10f);
        }
        float* fr = wl;
        fr[tx] = s;
        __syncthreads();
        for (int off = 128; off > 0; off >>= 1) {
            if (tx < off) fr[tx] += fr[tx + off];
            __syncthreads();
        }
        if (tx == 0) {
            out[LOSS_OFF] = BETA * atomicAdd(loss_ws, 0.f) / 2097152.f;
            out[PERP_OFF] = expf(-fr[0]);
        }
    }
}

extern "C" void kernel_launch(void* const* d_in, const int* in_sizes, int n_in,
                              void* d_out, int out_size, void* d_ws, size_t ws_size,
                              hipStream_t stream)
{
    const float* z = (const float*)d_in[0];
    const float* w = (const float*)d_in[1];
    float* out     = (float*)d_out;
    float* loss_ws = (float*)d_ws;
    int*   ticket  = (int*)((char*)d_ws + 4);
    int*   hist    = (int*)((char*)d_ws + 16);
    float* wnorm   = (float*)((char*)d_ws + 16400);

    hipMemsetAsync(d_ws, 0, 16 + 4096 * sizeof(int), stream);
    vq_wnorm<<<16, 256, 0, stream>>>(w, wnorm);
    vq_main<<<512, 256, 0, stream>>>(z, w, wnorm, out, loss_ws, ticket, hist);
}